// Round 1
// baseline (12.744 us; speedup 1.0000x reference)
//
#include <hip/hip_runtime.h>
#include <math.h>

#define EPS 1e-8f
#define D 128
#define K 5

// Kernel 1: one wave (64 lanes) per batch row. Each lane holds a float2
// slice of the D=128 row. Computes pos-cosine + mean of K neg-cosines,
// then block-reduces 4 waves -> one (pos_sum, neg_sum) pair per block.
__global__ __launch_bounds__(256) void simloss_partial(
    const float* __restrict__ ue,      // [B, D] user_embeddings
    const float* __restrict__ se,      // [B, D] subreddit_embeddings
    const float* __restrict__ tu,      // [NU, D] total_user_embeddings
    const float* __restrict__ ts,      // [NS, D] total_subreddit_embeddings
    const int*   __restrict__ busers,  // [B]
    const int*   __restrict__ negidx,  // [B, K]
    float* __restrict__ partials,      // [gridDim.x * 2]
    int B)
{
    const int lane = threadIdx.x & 63;
    const int wave = threadIdx.x >> 6;
    const int row  = blockIdx.x * 4 + wave;

    float pos = 0.0f, neg = 0.0f;
    if (row < B) {
        const float2 a = ((const float2*)(ue + (size_t)row * D))[lane];
        const float2 b = ((const float2*)(se + (size_t)row * D))[lane];
        float dot = a.x * b.x + a.y * b.y;
        float na  = a.x * a.x + a.y * a.y;
        float nb  = b.x * b.x + b.y * b.y;

        const int uidx = busers[row];
        const float2 c = ((const float2*)(tu + (size_t)uidx * D))[lane];
        float nc = c.x * c.x + c.y * c.y;

        float dk[K], nk[K];
        #pragma unroll
        for (int k = 0; k < K; ++k) {
            const int ni = negidx[row * K + k];
            const float2 e = ((const float2*)(ts + (size_t)ni * D))[lane];
            dk[k] = c.x * e.x + c.y * e.y;
            nk[k] = e.x * e.x + e.y * e.y;
        }

        // Wave-wide butterfly reduction of all 14 scalars.
        #pragma unroll
        for (int off = 32; off > 0; off >>= 1) {
            dot += __shfl_xor(dot, off);
            na  += __shfl_xor(na,  off);
            nb  += __shfl_xor(nb,  off);
            nc  += __shfl_xor(nc,  off);
            #pragma unroll
            for (int k = 0; k < K; ++k) {
                dk[k] += __shfl_xor(dk[k], off);
                nk[k] += __shfl_xor(nk[k], off);
            }
        }

        pos = dot / (fmaxf(sqrtf(na), EPS) * fmaxf(sqrtf(nb), EPS));

        const float rc = fmaxf(sqrtf(nc), EPS);
        float s = 0.0f;
        #pragma unroll
        for (int k = 0; k < K; ++k)
            s += dk[k] / (rc * fmaxf(sqrtf(nk[k]), EPS));
        neg = s * (1.0f / K);
    }

    __shared__ float sp[4], sn[4];
    if (lane == 0) { sp[wave] = pos; sn[wave] = neg; }
    __syncthreads();
    if (threadIdx.x == 0) {
        partials[blockIdx.x * 2 + 0] = sp[0] + sp[1] + sp[2] + sp[3];
        partials[blockIdx.x * 2 + 1] = sn[0] + sn[1] + sn[2] + sn[3];
    }
}

// Kernel 2: single block reduces nblocks (pos,neg) pairs -> final scalar.
__global__ __launch_bounds__(1024) void simloss_final(
    const float* __restrict__ partials, float* __restrict__ out,
    int nblocks, float invB)
{
    const int t = threadIdx.x;
    float p = 0.0f, n = 0.0f;
    if (t < nblocks) {
        p = partials[t * 2 + 0];
        n = partials[t * 2 + 1];
    }
    #pragma unroll
    for (int off = 32; off > 0; off >>= 1) {
        p += __shfl_xor(p, off);
        n += __shfl_xor(n, off);
    }
    __shared__ float lp[16], ln[16];
    const int lane = t & 63, wave = t >> 6;
    if (lane == 0) { lp[wave] = p; ln[wave] = n; }
    __syncthreads();
    if (t == 0) {
        float tp = 0.0f, tn = 0.0f;
        #pragma unroll
        for (int w = 0; w < 16; ++w) { tp += lp[w]; tn += ln[w]; }
        out[0] = (1.0f - tp * invB) + tn * invB;
    }
}

extern "C" void kernel_launch(void* const* d_in, const int* in_sizes, int n_in,
                              void* d_out, int out_size, void* d_ws, size_t ws_size,
                              hipStream_t stream) {
    const float* ue = (const float*)d_in[0];
    const float* se = (const float*)d_in[1];
    const float* tu = (const float*)d_in[2];
    const float* ts = (const float*)d_in[3];
    const int*   bu = (const int*)d_in[4];
    const int*   ni = (const int*)d_in[5];
    float* out = (float*)d_out;

    const int B = in_sizes[0] / D;              // 4096
    const int nblocks = (B + 3) / 4;            // 1024 (one wave per row, 4 waves/block)
    float* partials = (float*)d_ws;             // nblocks*2 floats = 8 KB

    simloss_partial<<<nblocks, 256, 0, stream>>>(ue, se, tu, ts, bu, ni, partials, B);
    simloss_final<<<1, 1024, 0, stream>>>(partials, out, nblocks, 1.0f / (float)B);
}

// Round 2
// 11.286 us; speedup vs baseline: 1.1292x; 1.1292x over previous
//
#include <hip/hip_runtime.h>
#include <math.h>

#define EPS 1e-8f
#define D 128
#define K 5

// Kernel 1: 32 lanes per batch row (2 rows per wave). Each lane holds a
// float4 slice (32 lanes x 16B = 512B = one D=128 row). Computes
// pos-cosine + mean of K neg-cosines per row, reduces within the 32-lane
// half-wave, then block-reduces 8 rows -> one (pos_sum, neg_sum) pair.
__global__ __launch_bounds__(256) void simloss_partial(
    const float* __restrict__ ue,      // [B, D]
    const float* __restrict__ se,      // [B, D]
    const float* __restrict__ tu,      // [NU, D]
    const float* __restrict__ ts,      // [NS, D]
    const int*   __restrict__ busers,  // [B]
    const int*   __restrict__ negidx,  // [B, K]
    float* __restrict__ partials,      // [gridDim.x * 2]
    int B)
{
    const int tid = blockIdx.x * 256 + threadIdx.x;
    const int row = tid >> 5;          // one row per 32 lanes
    const int r   = threadIdx.x & 31;  // lane within row

    float pos = 0.0f, neg = 0.0f;
    if (row < B) {
        // Issue index loads first (uniform within the 32-lane group).
        const int uidx = busers[row];
        int nidx[K];
        #pragma unroll
        for (int k = 0; k < K; ++k) nidx[k] = negidx[row * K + k];

        const float4 a = ((const float4*)(ue + (size_t)row * D))[r];
        const float4 b = ((const float4*)(se + (size_t)row * D))[r];
        float dot = a.x*b.x + a.y*b.y + a.z*b.z + a.w*b.w;
        float na  = a.x*a.x + a.y*a.y + a.z*a.z + a.w*a.w;
        float nb  = b.x*b.x + b.y*b.y + b.z*b.z + b.w*b.w;

        const float4 c = ((const float4*)(tu + (size_t)uidx * D))[r];
        float nc = c.x*c.x + c.y*c.y + c.z*c.z + c.w*c.w;

        float dk[K], nk[K];
        #pragma unroll
        for (int k = 0; k < K; ++k) {
            const float4 e = ((const float4*)(ts + (size_t)nidx[k] * D))[r];
            dk[k] = c.x*e.x + c.y*e.y + c.z*e.z + c.w*e.w;
            nk[k] = e.x*e.x + e.y*e.y + e.z*e.z + e.w*e.w;
        }

        // Butterfly reduction within each 32-lane half (offsets < 32 keep
        // the exchange inside the half-wave).
        #pragma unroll
        for (int off = 16; off > 0; off >>= 1) {
            dot += __shfl_xor(dot, off);
            na  += __shfl_xor(na,  off);
            nb  += __shfl_xor(nb,  off);
            nc  += __shfl_xor(nc,  off);
            #pragma unroll
            for (int k = 0; k < K; ++k) {
                dk[k] += __shfl_xor(dk[k], off);
                nk[k] += __shfl_xor(nk[k], off);
            }
        }

        // norms ~ sqrt(128) >> eps, rsqrtf error ~1e-6 << 2e-2 threshold
        pos = dot * rsqrtf(fmaxf(na, EPS * EPS)) * rsqrtf(fmaxf(nb, EPS * EPS));

        const float rc = rsqrtf(fmaxf(nc, EPS * EPS));
        float s = 0.0f;
        #pragma unroll
        for (int k = 0; k < K; ++k)
            s += dk[k] * rc * rsqrtf(fmaxf(nk[k], EPS * EPS));
        neg = s * (1.0f / K);
    }

    __shared__ float sp[8], sn[8];
    if (r == 0) { sp[threadIdx.x >> 5] = pos; sn[threadIdx.x >> 5] = neg; }
    __syncthreads();
    if (threadIdx.x == 0) {
        float tp = 0.0f, tn = 0.0f;
        #pragma unroll
        for (int i = 0; i < 8; ++i) { tp += sp[i]; tn += sn[i]; }
        partials[blockIdx.x * 2 + 0] = tp;
        partials[blockIdx.x * 2 + 1] = tn;
    }
}

// Kernel 2: single block reduces nblocks (pos,neg) pairs -> final scalar.
__global__ __launch_bounds__(512) void simloss_final(
    const float* __restrict__ partials, float* __restrict__ out,
    int nblocks, float invB)
{
    const int t = threadIdx.x;
    float p = 0.0f, n = 0.0f;
    if (t < nblocks) {
        p = partials[t * 2 + 0];
        n = partials[t * 2 + 1];
    }
    #pragma unroll
    for (int off = 32; off > 0; off >>= 1) {
        p += __shfl_xor(p, off);
        n += __shfl_xor(n, off);
    }
    __shared__ float lp[8], ln[8];
    const int lane = t & 63, wave = t >> 6;
    if (lane == 0) { lp[wave] = p; ln[wave] = n; }
    __syncthreads();
    if (t == 0) {
        float tp = 0.0f, tn = 0.0f;
        #pragma unroll
        for (int w = 0; w < 8; ++w) { tp += lp[w]; tn += ln[w]; }
        out[0] = (1.0f - tp * invB) + tn * invB;
    }
}

extern "C" void kernel_launch(void* const* d_in, const int* in_sizes, int n_in,
                              void* d_out, int out_size, void* d_ws, size_t ws_size,
                              hipStream_t stream) {
    const float* ue = (const float*)d_in[0];
    const float* se = (const float*)d_in[1];
    const float* tu = (const float*)d_in[2];
    const float* ts = (const float*)d_in[3];
    const int*   bu = (const int*)d_in[4];
    const int*   ni = (const int*)d_in[5];
    float* out = (float*)d_out;

    const int B = in_sizes[0] / D;               // 4096
    const int nblocks = (B * 32 + 255) / 256;    // 512 (8 rows per 256-thr block)
    float* partials = (float*)d_ws;              // nblocks*2 floats = 4 KB

    simloss_partial<<<nblocks, 256, 0, stream>>>(ue, se, tu, ts, bu, ni, partials, B);
    simloss_final<<<1, 512, 0, stream>>>(partials, out, nblocks, 1.0f / (float)B);
}